// Round 1
// 1384.466 us; speedup vs baseline: 1.3965x; 1.3965x over previous
//
#include <hip/hip_runtime.h>
#include <stdint.h>

#define BB 4
#define SS 8192
#define DD 1024
#define HH 8
#define DKK 128
#define EE 129            // DK + 1 (pos concat)
#define MM (BB * SS)      // 32768

typedef __attribute__((ext_vector_type(8))) short short8;
typedef __attribute__((ext_vector_type(4))) float floatx4;

__device__ __forceinline__ float bf2f(unsigned short u) {
    union { unsigned int i; float f; } v; v.i = ((unsigned int)u) << 16; return v.f;
}
__device__ __forceinline__ unsigned short f2bf(float f) {
    union { float f; unsigned int i; } v; v.f = f;
    unsigned int x = v.i;
    return (unsigned short)((x + 0x7FFFu + ((x >> 16) & 1u)) >> 16);
}

__device__ __forceinline__ void gld_lds16(const unsigned short* g, unsigned short* l) {
    __builtin_amdgcn_global_load_lds((const __attribute__((address_space(1))) void*)g,
                                     (__attribute__((address_space(3))) void*)l, 16, 0, 0);
}

// ---------------------------------------------------------------------------
// fp32 -> bf16 elementwise (vectorized), n4 = count of float4 groups
// ---------------------------------------------------------------------------
__global__ __launch_bounds__(256)
void conv_bf16(const float* __restrict__ in, unsigned short* __restrict__ out, int n4)
{
    int idx = blockIdx.x * 256 + threadIdx.x;
    const int stride = gridDim.x * 256;
    for (; idx < n4; idx += stride) {
        const float4 v = ((const float4*)in)[idx];
        ushort4 o;
        o.x = f2bf(v.x); o.y = f2bf(v.y); o.z = f2bf(v.z); o.w = f2bf(v.w);
        ((ushort4*)out)[idx] = o;
    }
}

// Wfc (1024 x 1032) fp32 -> (1024 x 1088) bf16, pad K with zeros
__global__ __launch_bounds__(256)
void conv_wfc(const float* __restrict__ in, unsigned short* __restrict__ out)
{
    int idx = blockIdx.x * 256 + threadIdx.x;
    const int stride = gridDim.x * 256;
    const int total = 1024 * 1088;
    for (; idx < total; idx += stride) {
        const int n = idx / 1088, k = idx - n * 1088;
        out[idx] = (k < 1032) ? f2bf(in[n * 1032 + k]) : (unsigned short)0;
    }
}

// ---------------------------------------------------------------------------
// MFMA GEMM: C = A @ B^T (+bias). A (M,K) bf16 row-major, B (N,K) bf16
// row-major. 128x128 tile, BK=64, 4 waves, 16x16x32 bf16 MFMA, 4x4 frags.
// MODE 0: fp32 C (M,1024) + bias         (final fc)
// MODE 1: bf16 out (B,H,S,129) + bias + pos at e=0        (Q projection)
// MODE 2: bias + per-head LayerNorm, TRANSPOSED bf16 out  (K/V projections)
//         KT[((b*H+h)*128 + d)*SS + s]   (no pos column)
// grid: (N/128, M/128)  -> n0 = bx*128 (head for MODE1/2), m0 = by*128
// ---------------------------------------------------------------------------
template<int MODE>
__global__ __launch_bounds__(256)
void gemm_bt(const unsigned short* __restrict__ A, const unsigned short* __restrict__ Bm,
             int K, const float* __restrict__ bias,
             const float* __restrict__ g, const float* __restrict__ beta,
             const float* __restrict__ pos,
             float* __restrict__ Cf, unsigned short* __restrict__ Cb)
{
    __shared__ unsigned short ABs[2 * 128 * 64];   // As | Bs, reused as transpose buf
    __shared__ float red[128][4];
    unsigned short* const As = ABs;
    unsigned short* const Bs = ABs + 128 * 64;

    const int tid  = threadIdx.x;
    const int lane = tid & 63, wid = tid >> 6;
    const int lr = lane & 15, lg = lane >> 4;
    const int wm = wid >> 1,  wn = wid & 1;
    const int n0 = blockIdx.x * 128;
    const int m0 = blockIdx.y * 128;

    floatx4 acc[4][4];
#pragma unroll
    for (int i = 0; i < 4; ++i)
#pragma unroll
        for (int j = 0; j < 4; ++j) acc[i][j] = (floatx4){0.f, 0.f, 0.f, 0.f};

    const int srow = lane >> 3;        // 0..7
    const int scol = (lane & 7) * 8;   // k offset (shorts) within the 64-wide tile

    for (int k0 = 0; k0 < K; k0 += 64) {
#pragma unroll
        for (int c = 0; c < 4; ++c) {
            const int j = wid * 4 + c;                   // 0..15: 8 rows per call
            const unsigned short* gA = A  + (size_t)(m0 + j * 8 + srow) * K + (k0 + scol);
            const unsigned short* gB = Bm + (size_t)(n0 + j * 8 + srow) * K + (k0 + scol);
            gld_lds16(gA, &As[j * 512]);
            gld_lds16(gB, &Bs[j * 512]);
        }
        __syncthreads();
#pragma unroll
        for (int kk = 0; kk < 64; kk += 32) {
            short8 af[4], bf[4];
#pragma unroll
            for (int f = 0; f < 4; ++f) {
                af[f] = *(const short8*)&As[(wm * 64 + f * 16 + lr) * 64 + kk + lg * 8];
                bf[f] = *(const short8*)&Bs[(wn * 64 + f * 16 + lr) * 64 + kk + lg * 8];
            }
#pragma unroll
            for (int fi = 0; fi < 4; ++fi)
#pragma unroll
                for (int fj = 0; fj < 4; ++fj)
                    acc[fi][fj] = __builtin_amdgcn_mfma_f32_16x16x32_bf16(
                        af[fi], bf[fj], acc[fi][fj], 0, 0, 0);
        }
        __syncthreads();
    }

    // bias (reference adds bias before LN)
    float bb[4];
#pragma unroll
    for (int fj = 0; fj < 4; ++fj) bb[fj] = bias[n0 + wn * 64 + fj * 16 + lr];
#pragma unroll
    for (int fi = 0; fi < 4; ++fi)
#pragma unroll
        for (int fj = 0; fj < 4; ++fj)
#pragma unroll
            for (int r = 0; r < 4; ++r) acc[fi][fj][r] += bb[fj];

    if (MODE == 0) {
#pragma unroll
        for (int fi = 0; fi < 4; ++fi)
#pragma unroll
            for (int r = 0; r < 4; ++r) {
                const int m = m0 + wm * 64 + fi * 16 + lg * 4 + r;
#pragma unroll
                for (int fj = 0; fj < 4; ++fj)
                    Cf[(size_t)m * 1024 + n0 + wn * 64 + fj * 16 + lr] = acc[fi][fj][r];
            }
        return;
    }

    if (MODE == 2) {
        float gv[4], bv[4];
#pragma unroll
        for (int fj = 0; fj < 4; ++fj) {
            gv[fj] = g[n0 + wn * 64 + fj * 16 + lr];     // g is (H,128) flat = 1024
            bv[fj] = beta[n0 + wn * 64 + fj * 16 + lr];
        }
        // per-row partial sums over this wave's 64 cols, then cross-wave via LDS
#pragma unroll
        for (int fi = 0; fi < 4; ++fi)
#pragma unroll
            for (int r = 0; r < 4; ++r) {
                float p1 = 0.f, p2 = 0.f;
#pragma unroll
                for (int fj = 0; fj < 4; ++fj) {
                    const float v = acc[fi][fj][r];
                    p1 += v; p2 += v * v;
                }
#pragma unroll
                for (int msk = 1; msk < 16; msk <<= 1) {
                    p1 += __shfl_xor(p1, msk);
                    p2 += __shfl_xor(p2, msk);
                }
                if (lr == 0) {
                    const int row = wm * 64 + fi * 16 + lg * 4 + r;
                    red[row][wn * 2]     = p1;
                    red[row][wn * 2 + 1] = p2;
                }
            }
        __syncthreads();
#pragma unroll
        for (int fi = 0; fi < 4; ++fi)
#pragma unroll
            for (int r = 0; r < 4; ++r) {
                const int row = wm * 64 + fi * 16 + lg * 4 + r;
                const float s1 = red[row][0] + red[row][2];
                const float s2 = red[row][1] + red[row][3];
                const float mean = s1 * (1.f / 128.f);
                const float var  = s2 * (1.f / 128.f) - mean * mean;
                const float inv  = rsqrtf(var + 1e-5f);
#pragma unroll
                for (int fj = 0; fj < 4; ++fj)
                    acc[fi][fj][r] = (acc[fi][fj][r] - mean) * inv * gv[fj] + bv[fj];
            }

        // ----- transposed store via LDS: two 64-feature passes reusing ABs ----
        // tile T[nl][ml], nl = feature within half (0..63), ml = s within tile,
        // padded stride 132 shorts -> 64*132 = 8448 shorts <= 16384 available.
        const int h = n0 >> 7;
        const int b = m0 >> 13, sbase = m0 & (SS - 1);
        const size_t rowbase = (size_t)(b * HH + h) * 128;
#pragma unroll
        for (int p = 0; p < 2; ++p) {
            __syncthreads();                      // protect prior ABs readers
            if (wn == p) {
#pragma unroll
                for (int fi = 0; fi < 4; ++fi)
#pragma unroll
                    for (int fj = 0; fj < 4; ++fj) {
                        const int nl = fj * 16 + lr;              // 0..63
                        const int ml = wm * 64 + fi * 16 + lg * 4;
                        ushort4 w;
                        w.x = f2bf(acc[fi][fj][0]); w.y = f2bf(acc[fi][fj][1]);
                        w.z = f2bf(acc[fi][fj][2]); w.w = f2bf(acc[fi][fj][3]);
                        *(ushort4*)&ABs[nl * 132 + ml] = w;
                    }
            }
            __syncthreads();
            // readback: 64 rows x 32 ushort4 = 2048 chunks over 256 threads
#pragma unroll
            for (int it = 0; it < 8; ++it) {
                const int idx = it * 256 + tid;
                const int dd = idx >> 5;          // 0..63
                const int c4 = idx & 31;          // ushort4 within row
                const ushort4 v = *(const ushort4*)&ABs[dd * 132 + c4 * 4];
                *(ushort4*)&Cb[(rowbase + p * 64 + dd) * SS + sbase + c4 * 4] = v;
            }
        }
        return;
    }

    // MODE 1: store bf16 (B,H,S,129), pos at e=0
    const int h = n0 >> 7;
#pragma unroll
    for (int fi = 0; fi < 4; ++fi)
#pragma unroll
        for (int r = 0; r < 4; ++r) {
            const int m = m0 + wm * 64 + fi * 16 + lg * 4 + r;
            const int b = m >> 13, s = m & (SS - 1);
            const size_t base = (((size_t)b * HH + h) * SS + s) * EE;
#pragma unroll
            for (int fj = 0; fj < 4; ++fj)
                Cb[base + 1 + wn * 64 + fj * 16 + lr] = f2bf(acc[fi][fj][r]);
            if (wn == 0 && lr == 0)
                Cb[base] = f2bf(pos[((size_t)b << 13) + s]);
        }
}

// ---------------------------------------------------------------------------
// p_attn core (MFMA): P[1+d][1+e] += (1/S) sum_s KT[bh,d,s]*VT[bh,e,s]
// grid (BB*HH, 16): each block does a 128x128 output tile over 512 s-values.
// ---------------------------------------------------------------------------
__global__ __launch_bounds__(256)
void pattm(const unsigned short* __restrict__ KT, const unsigned short* __restrict__ VT,
           float* __restrict__ P)
{
    __shared__ unsigned short ABs[2 * 128 * 64];
    unsigned short* const As = ABs;
    unsigned short* const Bs = ABs + 128 * 64;

    const int tid  = threadIdx.x;
    const int lane = tid & 63, wid = tid >> 6;
    const int lr = lane & 15, lg = lane >> 4;
    const int wm = wid >> 1,  wn = wid & 1;
    const int bh = blockIdx.x;

    const unsigned short* A = KT + (size_t)bh * 128 * SS;
    const unsigned short* B = VT + (size_t)bh * 128 * SS;

    floatx4 acc[4][4];
#pragma unroll
    for (int i = 0; i < 4; ++i)
#pragma unroll
        for (int j = 0; j < 4; ++j) acc[i][j] = (floatx4){0.f, 0.f, 0.f, 0.f};

    const int srow = lane >> 3;
    const int scol = (lane & 7) * 8;
    const int sBeg = blockIdx.y * (SS / 16);

    for (int k0 = sBeg; k0 < sBeg + SS / 16; k0 += 64) {
#pragma unroll
        for (int c = 0; c < 4; ++c) {
            const int j = wid * 4 + c;
            gld_lds16(A + (size_t)(j * 8 + srow) * SS + k0 + scol, &As[j * 512]);
            gld_lds16(B + (size_t)(j * 8 + srow) * SS + k0 + scol, &Bs[j * 512]);
        }
        __syncthreads();
#pragma unroll
        for (int kk = 0; kk < 64; kk += 32) {
            short8 af[4], bf[4];
#pragma unroll
            for (int f = 0; f < 4; ++f) {
                af[f] = *(const short8*)&As[(wm * 64 + f * 16 + lr) * 64 + kk + lg * 8];
                bf[f] = *(const short8*)&Bs[(wn * 64 + f * 16 + lr) * 64 + kk + lg * 8];
            }
#pragma unroll
            for (int fi = 0; fi < 4; ++fi)
#pragma unroll
                for (int fj = 0; fj < 4; ++fj)
                    acc[fi][fj] = __builtin_amdgcn_mfma_f32_16x16x32_bf16(
                        af[fi], bf[fj], acc[fi][fj], 0, 0, 0);
        }
        __syncthreads();
    }

    const float sc = 1.f / (float)SS;
    float* Pp = P + (size_t)bh * (EE * EE);
#pragma unroll
    for (int fi = 0; fi < 4; ++fi)
#pragma unroll
        for (int r = 0; r < 4; ++r) {
            const int row = 1 + wm * 64 + fi * 16 + lg * 4 + r;
#pragma unroll
            for (int fj = 0; fj < 4; ++fj) {
                const int col = 1 + wn * 64 + fj * 16 + lr;
                atomicAdd(&Pp[row * EE + col], acc[fi][fj][r] * sc);
            }
        }
}

// ---------------------------------------------------------------------------
// p_attn pos rim: P[1+d][0] = (1/S) sum_s KT[d,s]*pos,  P[0][1+e] = sum VT*pos,
// P[0][0] = sum pos^2.  grid (BB*HH, 4): s-split with atomicAdd.
// ---------------------------------------------------------------------------
__global__ __launch_bounds__(256)
void pedge(const unsigned short* __restrict__ KT, const unsigned short* __restrict__ VT,
           const float* __restrict__ pos, float* __restrict__ P)
{
    __shared__ float posS[1024];
    const int bh = blockIdx.x, b = bh >> 3;
    const int t = threadIdx.x;
    const int d = t & 127;
    const unsigned short* Row = ((t < 128) ? KT : VT) + ((size_t)bh * 128 + d) * SS;
    const float* pb = pos + ((size_t)b << 13);
    const int c0beg = blockIdx.y * (SS / 4), c0end = c0beg + (SS / 4);

    float d0 = 0.f, d1 = 0.f, d2 = 0.f, d3 = 0.f, p2 = 0.f;
    for (int c0 = c0beg; c0 < c0end; c0 += 1024) {
        __syncthreads();
        for (int i = t; i < 1024; i += 256) posS[i] = pb[c0 + i];
        __syncthreads();
        for (int i = 0; i < 1024; i += 8) {
            const short8 kv = *(const short8*)&Row[c0 + i];
            d0 += bf2f((unsigned short)kv[0]) * posS[i + 0];
            d1 += bf2f((unsigned short)kv[1]) * posS[i + 1];
            d2 += bf2f((unsigned short)kv[2]) * posS[i + 2];
            d3 += bf2f((unsigned short)kv[3]) * posS[i + 3];
            d0 += bf2f((unsigned short)kv[4]) * posS[i + 4];
            d1 += bf2f((unsigned short)kv[5]) * posS[i + 5];
            d2 += bf2f((unsigned short)kv[6]) * posS[i + 6];
            d3 += bf2f((unsigned short)kv[7]) * posS[i + 7];
            if (t == 0) {
#pragma unroll
                for (int j = 0; j < 8; ++j) p2 += posS[i + j] * posS[i + j];
            }
        }
    }
    const float dot = (d0 + d1) + (d2 + d3);
    const float sc = 1.f / (float)SS;
    float* Pp = P + (size_t)bh * (EE * EE);
    if (t < 128) atomicAdd(&Pp[(1 + d) * EE], dot * sc);
    else         atomicAdd(&Pp[1 + d],        dot * sc);
    if (t == 0)  atomicAdd(&Pp[0],            p2 * sc);
}

// ---------------------------------------------------------------------------
// x[b,s, h*129+e] = sum_d Qc[bh,s,d] * P[bh,d,e]; bf16 out rows padded to 1088
// ---------------------------------------------------------------------------
__global__ __launch_bounds__(256)
void xq(const unsigned short* __restrict__ Qc, const float* __restrict__ P,
        unsigned short* __restrict__ Xout)
{
    __shared__ float Qs[64][132];
    __shared__ float Ps[32][132];
    const int tx = threadIdx.x, ty = threadIdx.y;
    const int t  = ty * 16 + tx;
    const int bh = blockIdx.x;
    const int b = bh >> 3, h = bh & 7;
    const int s0 = blockIdx.y * 64;
    const size_t qbase = ((size_t)bh * SS + s0) * EE;

    for (int idx = t; idx < 64 * EE; idx += 256) {
        const int r = idx / EE, e = idx - r * EE;
        Qs[r][e] = bf2f(Qc[qbase + (size_t)r * EE + e]);
    }

    float acc[4][9];
#pragma unroll
    for (int i = 0; i < 4; ++i)
#pragma unroll
        for (int j = 0; j < 9; ++j) acc[i][j] = 0.f;

    const float* Pb = P + (size_t)bh * (EE * EE);
    for (int dc = 0; dc < EE; dc += 32) {
        const int csz = (EE - dc < 32) ? (EE - dc) : 32;
        for (int idx = t; idx < csz * EE; idx += 256) {
            const int r = idx / EE, e = idx - r * EE;
            Ps[r][e] = Pb[(dc + r) * EE + e];
        }
        __syncthreads();
        for (int dd = 0; dd < csz; ++dd) {
            float q[4];
#pragma unroll
            for (int i = 0; i < 4; ++i) q[i] = Qs[ty * 4 + i][dc + dd];
#pragma unroll
            for (int j = 0; j < 9; ++j) {
                const int c = tx + 16 * j;
                if (c < EE) {
                    const float pv = Ps[dd][c];
#pragma unroll
                    for (int i = 0; i < 4; ++i) acc[i][j] += q[i] * pv;
                }
            }
        }
        __syncthreads();
    }

#pragma unroll
    for (int i = 0; i < 4; ++i) {
        const int s = s0 + ty * 4 + i;
        const size_t obase = ((size_t)b * SS + s) * 1088 + (size_t)h * EE;
#pragma unroll
        for (int j = 0; j < 9; ++j) {
            const int c = tx + 16 * j;
            if (c < EE) Xout[obase + c] = f2bf(acc[i][j]);
        }
    }
}

// ---------------------------------------------------------------------------
extern "C" void kernel_launch(void* const* d_in, const int* in_sizes, int n_in,
                              void* d_out, int out_size, void* d_ws, size_t ws_size,
                              hipStream_t stream)
{
    const float* query = (const float*)d_in[0];
    const float* key   = (const float*)d_in[1];
    const float* value = (const float*)d_in[2];
    const float* pos   = (const float*)d_in[3];
    const float* Wq    = (const float*)d_in[4];
    const float* bq    = (const float*)d_in[5];
    const float* Wk    = (const float*)d_in[6];
    const float* bk    = (const float*)d_in[7];
    const float* Wv    = (const float*)d_in[8];
    const float* bv    = (const float*)d_in[9];
    const float* gK    = (const float*)d_in[10];
    const float* betaK = (const float*)d_in[11];
    const float* gV    = (const float*)d_in[12];
    const float* betaV = (const float*)d_in[13];
    const float* Wfc   = (const float*)d_in[14];
    const float* bfc   = (const float*)d_in[15];
    float* out = (float*)d_out;

    // Workspace regions (unchanged footprint):
    //   REG_A @ 0      : bf16 X input staging; later padded x (spills into REG_B)
    //   REG_B @ R      : KT (64 MB transposed); later Wq-bf16 then x-spill; WfcB at +8 MB
    //   REG_C @ 2R     : VT (64 MB transposed); later Qc
    //   PREG  @ 3R     : W-bf16 during projections; then p_attn (2.13 MB)
    char* ws = (char*)d_ws;
    const size_t R = (size_t)BB * HH * SS * EE * 2;   // 67,633,152
    unsigned short* XA   = (unsigned short*)(ws);
    unsigned short* RB   = (unsigned short*)(ws + R);
    unsigned short* RC   = (unsigned short*)(ws + 2 * R);
    float*          P    = (float*)(ws + 3 * R);
    unsigned short* WB   = (unsigned short*)(ws + 3 * R);
    unsigned short* WqB  = RB;
    unsigned short* Xb   = XA;                                   // (32768 x 1088) bf16
    unsigned short* WfcB = (unsigned short*)(ws + R + (8u << 20));

    const dim3 gblk(256);
    const dim3 ggrid(8, 256);   // (N/128, M/128)

    // K projection -> KT (transposed, LN'd, no pos)
    conv_bf16<<<256, gblk, 0, stream>>>(Wk, WB, 262144);
    conv_bf16<<<2048, gblk, 0, stream>>>(key, XA, 8388608);
    gemm_bt<2><<<ggrid, gblk, 0, stream>>>(XA, WB, 1024, bk, gK, betaK, pos, nullptr, RB);
    // V projection -> VT
    conv_bf16<<<256, gblk, 0, stream>>>(Wv, WB, 262144);
    conv_bf16<<<2048, gblk, 0, stream>>>(value, XA, 8388608);
    gemm_bt<2><<<ggrid, gblk, 0, stream>>>(XA, WB, 1024, bv, gV, betaV, pos, nullptr, RC);
    // p_attn: MFMA core + pos rim
    hipMemsetAsync(P, 0, (size_t)BB * HH * EE * EE * sizeof(float), stream);
    pattm<<<dim3(BB * HH, 16), gblk, 0, stream>>>(RB, RC, P);
    pedge<<<dim3(BB * HH, 4), gblk, 0, stream>>>(RB, RC, pos, P);
    // Q projection (KT/VT regions now dead)
    conv_bf16<<<256, gblk, 0, stream>>>(Wq, WqB, 262144);
    conv_bf16<<<2048, gblk, 0, stream>>>(query, XA, 8388608);
    gemm_bt<1><<<ggrid, gblk, 0, stream>>>(XA, WqB, 1024, bq, nullptr, nullptr, pos, nullptr, RC);
    // x = Q @ p_attn  (padded rows of 1088, written over REG_A + spill)
    xq<<<dim3(BB * HH, SS / 64), dim3(16, 16), 0, stream>>>(RC, P, Xb);
    // final fc
    conv_wfc<<<1024, gblk, 0, stream>>>(Wfc, WfcB);
    gemm_bt<0><<<ggrid, gblk, 0, stream>>>(Xb, WfcB, 1088, bfc, nullptr, nullptr, nullptr, out, nullptr);
}

// Round 2
// 1090.169 us; speedup vs baseline: 1.7735x; 1.2700x over previous
//
#include <hip/hip_runtime.h>
#include <stdint.h>

#define BB 4
#define SS 8192
#define DD 1024
#define HH 8
#define DKK 128
#define EE 129            // DK + 1 (pos concat)
#define MM (BB * SS)      // 32768

typedef __attribute__((ext_vector_type(8))) short short8;
typedef __attribute__((ext_vector_type(4))) float floatx4;

__device__ __forceinline__ float bf2f(unsigned short u) {
    union { unsigned int i; float f; } v; v.i = ((unsigned int)u) << 16; return v.f;
}
__device__ __forceinline__ unsigned short f2bf(float f) {
    union { float f; unsigned int i; } v; v.f = f;
    unsigned int x = v.i;
    return (unsigned short)((x + 0x7FFFu + ((x >> 16) & 1u)) >> 16);
}

__device__ __forceinline__ void gld_lds16(const unsigned short* g, unsigned short* l) {
    __builtin_amdgcn_global_load_lds((const __attribute__((address_space(1))) void*)g,
                                     (__attribute__((address_space(3))) void*)l, 16, 0, 0);
}

// ---------------------------------------------------------------------------
// fp32 -> bf16 elementwise (vectorized), n4 = count of float4 groups
// ---------------------------------------------------------------------------
__global__ __launch_bounds__(256)
void conv_bf16(const float* __restrict__ in, unsigned short* __restrict__ out, int n4)
{
    int idx = blockIdx.x * 256 + threadIdx.x;
    const int stride = gridDim.x * 256;
    for (; idx < n4; idx += stride) {
        const float4 v = ((const float4*)in)[idx];
        ushort4 o;
        o.x = f2bf(v.x); o.y = f2bf(v.y); o.z = f2bf(v.z); o.w = f2bf(v.w);
        ((ushort4*)out)[idx] = o;
    }
}

// Wfc (1024 x 1032) fp32 -> (1024 x 1088) bf16, pad K with zeros
__global__ __launch_bounds__(256)
void conv_wfc(const float* __restrict__ in, unsigned short* __restrict__ out)
{
    int idx = blockIdx.x * 256 + threadIdx.x;
    const int stride = gridDim.x * 256;
    const int total = 1024 * 1088;
    for (; idx < total; idx += stride) {
        const int n = idx / 1088, k = idx - n * 1088;
        out[idx] = (k < 1032) ? f2bf(in[n * 1032 + k]) : (unsigned short)0;
    }
}

// ---------------------------------------------------------------------------
// MFMA GEMM: C = A @ B^T (+bias). A (M,K) bf16 row-major, B (N,K) bf16
// row-major. 128x128 tile, BK=64, 4 waves, 16x16x32 bf16 MFMA, 4x4 frags.
// MODE 0: fp32 C (M,1024) + bias         (final fc)
// MODE 1: bf16 dense Q out (B,H,S,128) + bias, no pos     (Q projection)
// MODE 2: bias + per-head LayerNorm, TRANSPOSED bf16 out  (K/V projections)
//         KT[((b*H+h)*128 + d)*SS + s]   (no pos column)
// grid: (N/128, M/128)  -> n0 = bx*128 (head for MODE1/2), m0 = by*128
// ---------------------------------------------------------------------------
template<int MODE>
__global__ __launch_bounds__(256)
void gemm_bt(const unsigned short* __restrict__ A, const unsigned short* __restrict__ Bm,
             int K, const float* __restrict__ bias,
             const float* __restrict__ g, const float* __restrict__ beta,
             const float* __restrict__ pos,
             float* __restrict__ Cf, unsigned short* __restrict__ Cb)
{
    __shared__ unsigned short ABs[2 * 128 * 64];   // As | Bs, reused as transpose buf
    __shared__ float red[128][4];
    unsigned short* const As = ABs;
    unsigned short* const Bs = ABs + 128 * 64;

    const int tid  = threadIdx.x;
    const int lane = tid & 63, wid = tid >> 6;
    const int lr = lane & 15, lg = lane >> 4;
    const int wm = wid >> 1,  wn = wid & 1;
    const int n0 = blockIdx.x * 128;
    const int m0 = blockIdx.y * 128;

    floatx4 acc[4][4];
#pragma unroll
    for (int i = 0; i < 4; ++i)
#pragma unroll
        for (int j = 0; j < 4; ++j) acc[i][j] = (floatx4){0.f, 0.f, 0.f, 0.f};

    const int srow = lane >> 3;        // 0..7
    const int scol = (lane & 7) * 8;   // k offset (shorts) within the 64-wide tile

    for (int k0 = 0; k0 < K; k0 += 64) {
#pragma unroll
        for (int c = 0; c < 4; ++c) {
            const int j = wid * 4 + c;                   // 0..15: 8 rows per call
            const unsigned short* gA = A  + (size_t)(m0 + j * 8 + srow) * K + (k0 + scol);
            const unsigned short* gB = Bm + (size_t)(n0 + j * 8 + srow) * K + (k0 + scol);
            gld_lds16(gA, &As[j * 512]);
            gld_lds16(gB, &Bs[j * 512]);
        }
        __syncthreads();
#pragma unroll
        for (int kk = 0; kk < 64; kk += 32) {
            short8 af[4], bf[4];
#pragma unroll
            for (int f = 0; f < 4; ++f) {
                af[f] = *(const short8*)&As[(wm * 64 + f * 16 + lr) * 64 + kk + lg * 8];
                bf[f] = *(const short8*)&Bs[(wn * 64 + f * 16 + lr) * 64 + kk + lg * 8];
            }
#pragma unroll
            for (int fi = 0; fi < 4; ++fi)
#pragma unroll
                for (int fj = 0; fj < 4; ++fj)
                    acc[fi][fj] = __builtin_amdgcn_mfma_f32_16x16x32_bf16(
                        af[fi], bf[fj], acc[fi][fj], 0, 0, 0);
        }
        __syncthreads();
    }

    // bias (reference adds bias before LN)
    float bb[4];
#pragma unroll
    for (int fj = 0; fj < 4; ++fj) bb[fj] = bias[n0 + wn * 64 + fj * 16 + lr];
#pragma unroll
    for (int fi = 0; fi < 4; ++fi)
#pragma unroll
        for (int fj = 0; fj < 4; ++fj)
#pragma unroll
            for (int r = 0; r < 4; ++r) acc[fi][fj][r] += bb[fj];

    if (MODE == 0) {
#pragma unroll
        for (int fi = 0; fi < 4; ++fi)
#pragma unroll
            for (int r = 0; r < 4; ++r) {
                const int m = m0 + wm * 64 + fi * 16 + lg * 4 + r;
#pragma unroll
                for (int fj = 0; fj < 4; ++fj)
                    Cf[(size_t)m * 1024 + n0 + wn * 64 + fj * 16 + lr] = acc[fi][fj][r];
            }
        return;
    }

    if (MODE == 2) {
        float gv[4], bv[4];
#pragma unroll
        for (int fj = 0; fj < 4; ++fj) {
            gv[fj] = g[n0 + wn * 64 + fj * 16 + lr];     // g is (H,128) flat = 1024
            bv[fj] = beta[n0 + wn * 64 + fj * 16 + lr];
        }
        // per-row partial sums over this wave's 64 cols, then cross-wave via LDS
#pragma unroll
        for (int fi = 0; fi < 4; ++fi)
#pragma unroll
            for (int r = 0; r < 4; ++r) {
                float p1 = 0.f, p2 = 0.f;
#pragma unroll
                for (int fj = 0; fj < 4; ++fj) {
                    const float v = acc[fi][fj][r];
                    p1 += v; p2 += v * v;
                }
#pragma unroll
                for (int msk = 1; msk < 16; msk <<= 1) {
                    p1 += __shfl_xor(p1, msk);
                    p2 += __shfl_xor(p2, msk);
                }
                if (lr == 0) {
                    const int row = wm * 64 + fi * 16 + lg * 4 + r;
                    red[row][wn * 2]     = p1;
                    red[row][wn * 2 + 1] = p2;
                }
            }
        __syncthreads();
#pragma unroll
        for (int fi = 0; fi < 4; ++fi)
#pragma unroll
            for (int r = 0; r < 4; ++r) {
                const int row = wm * 64 + fi * 16 + lg * 4 + r;
                const float s1 = red[row][0] + red[row][2];
                const float s2 = red[row][1] + red[row][3];
                const float mean = s1 * (1.f / 128.f);
                const float var  = s2 * (1.f / 128.f) - mean * mean;
                const float inv  = rsqrtf(var + 1e-5f);
#pragma unroll
                for (int fj = 0; fj < 4; ++fj)
                    acc[fi][fj][r] = (acc[fi][fj][r] - mean) * inv * gv[fj] + bv[fj];
            }

        // ----- transposed store via LDS: two 64-feature passes reusing ABs ----
        const int h = n0 >> 7;
        const int b = m0 >> 13, sbase = m0 & (SS - 1);
        const size_t rowbase = (size_t)(b * HH + h) * 128;
#pragma unroll
        for (int p = 0; p < 2; ++p) {
            __syncthreads();                      // protect prior ABs readers
            if (wn == p) {
#pragma unroll
                for (int fi = 0; fi < 4; ++fi)
#pragma unroll
                    for (int fj = 0; fj < 4; ++fj) {
                        const int nl = fj * 16 + lr;              // 0..63
                        const int ml = wm * 64 + fi * 16 + lg * 4;
                        ushort4 w;
                        w.x = f2bf(acc[fi][fj][0]); w.y = f2bf(acc[fi][fj][1]);
                        w.z = f2bf(acc[fi][fj][2]); w.w = f2bf(acc[fi][fj][3]);
                        *(ushort4*)&ABs[nl * 132 + ml] = w;
                    }
            }
            __syncthreads();
            // readback: 64 rows x 32 ushort4 = 2048 chunks over 256 threads
#pragma unroll
            for (int it = 0; it < 8; ++it) {
                const int idx = it * 256 + tid;
                const int dd = idx >> 5;          // 0..63
                const int c4 = idx & 31;          // ushort4 within row
                const ushort4 v = *(const ushort4*)&ABs[dd * 132 + c4 * 4];
                *(ushort4*)&Cb[(rowbase + p * 64 + dd) * SS + sbase + c4 * 4] = v;
            }
        }
        return;
    }

    // MODE 1: store bf16 dense Q (B,H,S,128), no pos column
    const int h = n0 >> 7;
#pragma unroll
    for (int fi = 0; fi < 4; ++fi)
#pragma unroll
        for (int r = 0; r < 4; ++r) {
            const int m = m0 + wm * 64 + fi * 16 + lg * 4 + r;
            const int b = m >> 13, s = m & (SS - 1);
            const size_t base = (((size_t)b * HH + h) * SS + s) * 128;
#pragma unroll
            for (int fj = 0; fj < 4; ++fj)
                Cb[base + wn * 64 + fj * 16 + lr] = f2bf(acc[fi][fj][r]);
        }
}

// ---------------------------------------------------------------------------
// p_attn core (MFMA): P[1+d][1+e] += (1/S) sum_s KT[bh,d,s]*VT[bh,e,s]
// grid (BB*HH, 16): each block does a 128x128 output tile over 512 s-values.
// ---------------------------------------------------------------------------
__global__ __launch_bounds__(256)
void pattm(const unsigned short* __restrict__ KT, const unsigned short* __restrict__ VT,
           float* __restrict__ P)
{
    __shared__ unsigned short ABs[2 * 128 * 64];
    unsigned short* const As = ABs;
    unsigned short* const Bs = ABs + 128 * 64;

    const int tid  = threadIdx.x;
    const int lane = tid & 63, wid = tid >> 6;
    const int lr = lane & 15, lg = lane >> 4;
    const int wm = wid >> 1,  wn = wid & 1;
    const int bh = blockIdx.x;

    const unsigned short* A = KT + (size_t)bh * 128 * SS;
    const unsigned short* B = VT + (size_t)bh * 128 * SS;

    floatx4 acc[4][4];
#pragma unroll
    for (int i = 0; i < 4; ++i)
#pragma unroll
        for (int j = 0; j < 4; ++j) acc[i][j] = (floatx4){0.f, 0.f, 0.f, 0.f};

    const int srow = lane >> 3;
    const int scol = (lane & 7) * 8;
    const int sBeg = blockIdx.y * (SS / 16);

    for (int k0 = sBeg; k0 < sBeg + SS / 16; k0 += 64) {
#pragma unroll
        for (int c = 0; c < 4; ++c) {
            const int j = wid * 4 + c;
            gld_lds16(A + (size_t)(j * 8 + srow) * SS + k0 + scol, &As[j * 512]);
            gld_lds16(B + (size_t)(j * 8 + srow) * SS + k0 + scol, &Bs[j * 512]);
        }
        __syncthreads();
#pragma unroll
        for (int kk = 0; kk < 64; kk += 32) {
            short8 af[4], bf[4];
#pragma unroll
            for (int f = 0; f < 4; ++f) {
                af[f] = *(const short8*)&As[(wm * 64 + f * 16 + lr) * 64 + kk + lg * 8];
                bf[f] = *(const short8*)&Bs[(wn * 64 + f * 16 + lr) * 64 + kk + lg * 8];
            }
#pragma unroll
            for (int fi = 0; fi < 4; ++fi)
#pragma unroll
                for (int fj = 0; fj < 4; ++fj)
                    acc[fi][fj] = __builtin_amdgcn_mfma_f32_16x16x32_bf16(
                        af[fi], bf[fj], acc[fi][fj], 0, 0, 0);
        }
        __syncthreads();
    }

    const float sc = 1.f / (float)SS;
    float* Pp = P + (size_t)bh * (EE * EE);
#pragma unroll
    for (int fi = 0; fi < 4; ++fi)
#pragma unroll
        for (int r = 0; r < 4; ++r) {
            const int row = 1 + wm * 64 + fi * 16 + lg * 4 + r;
#pragma unroll
            for (int fj = 0; fj < 4; ++fj) {
                const int col = 1 + wn * 64 + fj * 16 + lr;
                atomicAdd(&Pp[row * EE + col], acc[fi][fj][r] * sc);
            }
        }
}

// ---------------------------------------------------------------------------
// p_attn pos rim: P[1+d][0] = (1/S) sum_s KT[d,s]*pos,  P[0][1+e] = sum VT*pos,
// P[0][0] = sum pos^2.  grid (BB*HH, 4): s-split with atomicAdd.
// ---------------------------------------------------------------------------
__global__ __launch_bounds__(256)
void pedge(const unsigned short* __restrict__ KT, const unsigned short* __restrict__ VT,
           const float* __restrict__ pos, float* __restrict__ P)
{
    __shared__ float posS[1024];
    const int bh = blockIdx.x, b = bh >> 3;
    const int t = threadIdx.x;
    const int d = t & 127;
    const unsigned short* Row = ((t < 128) ? KT : VT) + ((size_t)bh * 128 + d) * SS;
    const float* pb = pos + ((size_t)b << 13);
    const int c0beg = blockIdx.y * (SS / 4), c0end = c0beg + (SS / 4);

    float d0 = 0.f, d1 = 0.f, d2 = 0.f, d3 = 0.f, p2 = 0.f;
    for (int c0 = c0beg; c0 < c0end; c0 += 1024) {
        __syncthreads();
        for (int i = t; i < 1024; i += 256) posS[i] = pb[c0 + i];
        __syncthreads();
        for (int i = 0; i < 1024; i += 8) {
            const short8 kv = *(const short8*)&Row[c0 + i];
            d0 += bf2f((unsigned short)kv[0]) * posS[i + 0];
            d1 += bf2f((unsigned short)kv[1]) * posS[i + 1];
            d2 += bf2f((unsigned short)kv[2]) * posS[i + 2];
            d3 += bf2f((unsigned short)kv[3]) * posS[i + 3];
            d0 += bf2f((unsigned short)kv[4]) * posS[i + 4];
            d1 += bf2f((unsigned short)kv[5]) * posS[i + 5];
            d2 += bf2f((unsigned short)kv[6]) * posS[i + 6];
            d3 += bf2f((unsigned short)kv[7]) * posS[i + 7];
            if (t == 0) {
#pragma unroll
                for (int j = 0; j < 8; ++j) p2 += posS[i + j] * posS[i + j];
            }
        }
    }
    const float dot = (d0 + d1) + (d2 + d3);
    const float sc = 1.f / (float)SS;
    float* Pp = P + (size_t)bh * (EE * EE);
    if (t < 128) atomicAdd(&Pp[(1 + d) * EE], dot * sc);
    else         atomicAdd(&Pp[1 + d],        dot * sc);
    if (t == 0)  atomicAdd(&Pp[0],            p2 * sc);
}

// ---------------------------------------------------------------------------
// xqm: x[b,s,h*129+e] = sum_d Q[bh,s,d]*P[bh,1+d,1..] + pos*P[bh,0,:]  (MFMA)
// A (Q rows) global->regs; B = P^T staged in LDS as bf16 hi+lo, XOR-swizzled.
// grid (BB*HH, SS/128), 256 thr = 4 waves x (32 s-rows x 128 e-cols).
// e=128 column + pos rank-1 handled exactly in fp32 in the epilogue.
// ---------------------------------------------------------------------------
__global__ __launch_bounds__(256)
void xqm(const unsigned short* __restrict__ Qd, const float* __restrict__ P,
         const float* __restrict__ pos, unsigned short* __restrict__ Xout)
{
    __shared__ unsigned short PTh[128 * 128];
    __shared__ unsigned short PTl[128 * 128];

    const int tid  = threadIdx.x;
    const int lane = tid & 63, wid = tid >> 6;
    const int lr = lane & 15, lg = lane >> 4;
    const int bh = blockIdx.x;
    const int b = bh >> 3, h = bh & 7;
    const int s0 = blockIdx.y * 128;
    const int ws0 = s0 + wid * 32;

    const float* Pp = P + (size_t)bh * (EE * EE);

    // A fragments: Q rows straight from global into registers
    short8 a[2][4];
    const size_t qrow0 = (size_t)bh * SS + ws0 + lr;
#pragma unroll
    for (int mf = 0; mf < 2; ++mf)
#pragma unroll
        for (int ks = 0; ks < 4; ++ks)
            a[mf][ks] = *(const short8*)&Qd[(qrow0 + mf * 16) * 128 + ks * 32 + lg * 8];

    // stage PT[e][d] = P[1+d][e] (hi+lo bf16), XOR-swizzled rows
    for (int idx = tid; idx < 16384; idx += 256) {
        const int e = idx & 127, d = idx >> 7;
        const float pv = Pp[(1 + d) * EE + e];
        const unsigned short hi = f2bf(pv);
        const unsigned short lo = f2bf(pv - bf2f(hi));
        const int sidx = (e * 128 + d) ^ ((e & 7) << 3);
        PTh[sidx] = hi;
        PTl[sidx] = lo;
    }
    __syncthreads();

    floatx4 acc[2][8];
#pragma unroll
    for (int mf = 0; mf < 2; ++mf)
#pragma unroll
        for (int nf = 0; nf < 8; ++nf) acc[mf][nf] = (floatx4){0.f, 0.f, 0.f, 0.f};

#pragma unroll
    for (int ks = 0; ks < 4; ++ks) {
        short8 bh8[8], bl8[8];
#pragma unroll
        for (int nf = 0; nf < 8; ++nf) {
            const int row = nf * 16 + lr;
            const int sidx = (row * 128 + ks * 32 + lg * 8) ^ ((row & 7) << 3);
            bh8[nf] = *(const short8*)&PTh[sidx];
            bl8[nf] = *(const short8*)&PTl[sidx];
        }
#pragma unroll
        for (int mf = 0; mf < 2; ++mf)
#pragma unroll
            for (int nf = 0; nf < 8; ++nf) {
                acc[mf][nf] = __builtin_amdgcn_mfma_f32_16x16x32_bf16(
                    a[mf][ks], bh8[nf], acc[mf][nf], 0, 0, 0);
                acc[mf][nf] = __builtin_amdgcn_mfma_f32_16x16x32_bf16(
                    a[mf][ks], bl8[nf], acc[mf][nf], 0, 0, 0);
            }
    }

    // rank-1 pos (x) P[0,:] in fp32
    float posr[2][4];
#pragma unroll
    for (int mf = 0; mf < 2; ++mf)
#pragma unroll
        for (int r = 0; r < 4; ++r)
            posr[mf][r] = pos[((size_t)b << 13) + ws0 + mf * 16 + lg * 4 + r];
    float p0c[8];
#pragma unroll
    for (int nf = 0; nf < 8; ++nf) p0c[nf] = Pp[nf * 16 + lr];
#pragma unroll
    for (int mf = 0; mf < 2; ++mf)
#pragma unroll
        for (int nf = 0; nf < 8; ++nf)
#pragma unroll
            for (int r = 0; r < 4; ++r)
                acc[mf][nf][r] += posr[mf][r] * p0c[nf];

    // store e = 0..127
#pragma unroll
    for (int mf = 0; mf < 2; ++mf)
#pragma unroll
        for (int r = 0; r < 4; ++r) {
            const int srow = ws0 + mf * 16 + lg * 4 + r;
            const size_t obase = ((size_t)b * SS + srow) * 1088 + (size_t)h * EE;
#pragma unroll
            for (int nf = 0; nf < 8; ++nf)
                Xout[obase + nf * 16 + lr] = f2bf(acc[mf][nf][r]);
        }

    // e = 128 column: dot over d in regs, reduce across lg, + pos term
    float dp0 = 0.f, dp1 = 0.f;
#pragma unroll
    for (int ks = 0; ks < 4; ++ks)
#pragma unroll
        for (int j = 0; j < 8; ++j) {
            const int d = ks * 32 + lg * 8 + j;
            const float pc = Pp[(1 + d) * EE + 128];
            dp0 += bf2f((unsigned short)a[0][ks][j]) * pc;
            dp1 += bf2f((unsigned short)a[1][ks][j]) * pc;
        }
    dp0 += __shfl_xor(dp0, 16); dp0 += __shfl_xor(dp0, 32);
    dp1 += __shfl_xor(dp1, 16); dp1 += __shfl_xor(dp1, 32);
    if (lg == 0) {
        const float p00 = Pp[128];   // P[0][128]
#pragma unroll
        for (int mf = 0; mf < 2; ++mf) {
            const int srow = ws0 + mf * 16 + lr;
            const float dp = (mf == 0) ? dp0 : dp1;
            const float xv = dp + pos[((size_t)b << 13) + srow] * p00;
            Xout[((size_t)b * SS + srow) * 1088 + (size_t)h * EE + 128] = f2bf(xv);
        }
    }
}

// ---------------------------------------------------------------------------
extern "C" void kernel_launch(void* const* d_in, const int* in_sizes, int n_in,
                              void* d_out, int out_size, void* d_ws, size_t ws_size,
                              hipStream_t stream)
{
    const float* query = (const float*)d_in[0];
    const float* key   = (const float*)d_in[1];
    const float* value = (const float*)d_in[2];
    const float* pos   = (const float*)d_in[3];
    const float* Wq    = (const float*)d_in[4];
    const float* bq    = (const float*)d_in[5];
    const float* Wk    = (const float*)d_in[6];
    const float* bk    = (const float*)d_in[7];
    const float* Wv    = (const float*)d_in[8];
    const float* bv    = (const float*)d_in[9];
    const float* gK    = (const float*)d_in[10];
    const float* betaK = (const float*)d_in[11];
    const float* gV    = (const float*)d_in[12];
    const float* betaV = (const float*)d_in[13];
    const float* Wfc   = (const float*)d_in[14];
    const float* bfc   = (const float*)d_in[15];
    float* out = (float*)d_out;

    // Workspace regions (unchanged footprint):
    //   REG_A @ 0      : bf16 X input staging; later padded x (spills into REG_B)
    //   REG_B @ R      : KT (64 MB transposed); later Wq-bf16 then x-spill; WfcB at +8 MB
    //   REG_C @ 2R     : VT (64 MB transposed); later Qd dense (64 MB)
    //   PREG  @ 3R     : W-bf16 during projections; then p_attn (2.13 MB)
    char* ws = (char*)d_ws;
    const size_t R = (size_t)BB * HH * SS * EE * 2;   // 67,633,152
    unsigned short* XA   = (unsigned short*)(ws);
    unsigned short* RB   = (unsigned short*)(ws + R);
    unsigned short* RC   = (unsigned short*)(ws + 2 * R);
    float*          P    = (float*)(ws + 3 * R);
    unsigned short* WB   = (unsigned short*)(ws + 3 * R);
    unsigned short* WqB  = RB;
    unsigned short* Xb   = XA;                                   // (32768 x 1088) bf16
    unsigned short* WfcB = (unsigned short*)(ws + R + (8u << 20));

    const dim3 gblk(256);
    const dim3 ggrid(8, 256);   // (N/128, M/128)

    // K projection -> KT (transposed, LN'd, no pos)
    conv_bf16<<<256, gblk, 0, stream>>>(Wk, WB, 262144);
    conv_bf16<<<2048, gblk, 0, stream>>>(key, XA, 8388608);
    gemm_bt<2><<<ggrid, gblk, 0, stream>>>(XA, WB, 1024, bk, gK, betaK, pos, nullptr, RB);
    // V projection -> VT
    conv_bf16<<<256, gblk, 0, stream>>>(Wv, WB, 262144);
    conv_bf16<<<2048, gblk, 0, stream>>>(value, XA, 8388608);
    gemm_bt<2><<<ggrid, gblk, 0, stream>>>(XA, WB, 1024, bv, gV, betaV, pos, nullptr, RC);
    // p_attn: MFMA core + pos rim
    hipMemsetAsync(P, 0, (size_t)BB * HH * EE * EE * sizeof(float), stream);
    pattm<<<dim3(BB * HH, 16), gblk, 0, stream>>>(RB, RC, P);
    pedge<<<dim3(BB * HH, 4), gblk, 0, stream>>>(RB, RC, pos, P);
    // Q projection -> dense Qd (B,H,S,128), KT/VT regions now dead
    conv_bf16<<<256, gblk, 0, stream>>>(Wq, WqB, 262144);
    conv_bf16<<<2048, gblk, 0, stream>>>(query, XA, 8388608);
    gemm_bt<1><<<ggrid, gblk, 0, stream>>>(XA, WqB, 1024, bq, nullptr, nullptr, pos, nullptr, RC);
    // x = Q @ p_attn via MFMA (padded rows of 1088, written over REG_A + spill)
    xqm<<<dim3(BB * HH, SS / 128), gblk, 0, stream>>>(RC, P, pos, Xb);
    // final fc
    conv_wfc<<<1024, gblk, 0, stream>>>(Wfc, WfcB);
    gemm_bt<0><<<ggrid, gblk, 0, stream>>>(Xb, WfcB, 1088, bfc, nullptr, nullptr, nullptr, out, nullptr);
}